// Round 1
// baseline (898.762 us; speedup 1.0000x reference)
//
#include <hip/hip_runtime.h>

#define NR 131072
#define FEA 512
#define MEM 320
#define NW 336            // 320 W rows + 10 sem rows + 6 zero pad
#define NCLS 10
#define SHRK 0.0025f
#define EPSV 1e-12f

typedef short bh8 __attribute__((ext_vector_type(8)));
typedef float f4  __attribute__((ext_vector_type(4)));

#define MFMA16 __builtin_amdgcn_mfma_f32_16x16x32_bf16

__device__ inline unsigned short f2b(float f) {
    union { float f; unsigned int u; } c; c.f = f;
    unsigned int u = c.u;
    u += 0x7FFFu + ((u >> 16) & 1u);
    return (unsigned short)(u >> 16);
}

__device__ inline float sigm(float x) { return 1.f / (1.f + __expf(-x)); }

// async global->LDS, 16B per lane, wave-uniform LDS base (lane*16 auto-offset)
__device__ inline void gld16(const unsigned short* g, unsigned short* l) {
    __builtin_amdgcn_global_load_lds(
        (const __attribute__((address_space(1))) unsigned int*)g,
        (__attribute__((address_space(3))) unsigned int*)l, 16, 0, 0);
}

// ---------- P1: cast W to bf16 [336][512] (rows 320..335 zeroed) + transposed [512][320] ----------
__global__ void cast_w(const float* __restrict__ W, unsigned short* __restrict__ Wb2,
                       unsigned short* __restrict__ Wt) {
    int idx = blockIdx.x * 256 + threadIdx.x;
    if (idx >= NW * FEA) return;
    if (idx < MEM * FEA) {
        int n = idx >> 9, k = idx & 511;
        unsigned short b = f2b(W[idx]);
        Wb2[idx] = b;
        Wt[k * MEM + n] = b;
    } else {
        Wb2[idx] = 0;     // pad rows (sem rows 320..329 overwritten by sem_kernel)
    }
}

// ---------- P2: exact fp32 sem_att [10][512]; also emit bf16 into Wb2 rows 320.. and semTb [512][32] ----------
__global__ void sem_kernel(const float* __restrict__ W, const float* __restrict__ wp,
                           const float* __restrict__ bp, const float* __restrict__ wi,
                           const float* __restrict__ bi, unsigned short* __restrict__ Wb2,
                           unsigned short* __restrict__ semTb, float* __restrict__ out2) {
    int c = blockIdx.x * 64 + threadIdx.x;  // 0..511
    float pa[8];
    for (int l = 0; l < NCLS; ++l) {
#pragma unroll
        for (int t = 0; t < 8; ++t) {
            int n = l * 8 + t;
            const float* wb = W + n * 2048 + c * 4;
            float wv[4] = {wb[0], wb[1], wb[2], wb[3]};
            float s = 0.f;
#pragma unroll
            for (int q = 0; q < 4; ++q) {
                float z = bp[q] + wp[q*4+0]*wv[0] + wp[q*4+1]*wv[1]
                                + wp[q*4+2]*wv[2] + wp[q*4+3]*wv[3];
                s += sigm(z) * wv[q];
            }
            pa[t] = 0.25f * s;
        }
        float s2 = 0.f;
#pragma unroll
        for (int q = 0; q < 8; ++q) {
            float z = bi[q];
#pragma unroll
            for (int t = 0; t < 8; ++t) z += wi[q*8+t] * pa[t];
            s2 += sigm(z) * pa[q];
        }
        float v = 0.125f * s2;
        out2[l * FEA + c] = v;
        unsigned short b = f2b(v);
        Wb2[(MEM + l) * FEA + c] = b;   // class rows appended to GEMM1 B-matrix
        semTb[c * 32 + l] = b;          // B for final GEMM: [fea][k], k<10 live
    }
#pragma unroll
    for (int k = NCLS; k < 32; ++k) semTb[c * 32 + k] = 0;
}

// ---------- main fused kernel: 64 rows / block, 4 waves ----------
__global__ __launch_bounds__(256, 2) void fused_kernel(
    const float* __restrict__ x, const unsigned short* __restrict__ Wb2,
    const unsigned short* __restrict__ Wt, const unsigned short* __restrict__ semTb,
    float* __restrict__ out0, float* __restrict__ out1, float* __restrict__ out3)
{
    // [0,21504): GEMM1 stage dbuf 2x[336][32]; reused as att [64][328] after GEMM1
    // [21504,24064): att2 [64][40]
    __shared__ unsigned short lds[24064];   // 48,128 B -> 2 blocks/CU
    unsigned short* stg   = lds;
    unsigned short* attL  = lds;
    unsigned short* att2L = lds + 21504;

    const int tid  = threadIdx.x;
    const int wave = tid >> 6, lane = tid & 63;
    const int quad = lane >> 4, l16 = lane & 15;
    const int m0   = wave << 4;
    const int grow = lane >> 2, gcol = (lane & 3) << 3;
    const long rowbase = (long)blockIdx.x * 64;
    const float* xrow = x + (rowbase + m0 + l16) * FEA + (quad << 3);

    // ======== GEMM1 (+class logits): logits = x @ [W;sem]^T  M=64,N=336,K=512 ========
    f4 acc[21];
#pragma unroll
    for (int t = 0; t < 21; ++t) acc[t] = (f4){0.f, 0.f, 0.f, 0.f};

    // stage K-step S cols into buffer BUF: 21 groups of 16 rows, wave-uniform split
#define STAGE(BUF, S) {                                                          \
        const unsigned short* gs_ = Wb2 + ((S) << 5) + grow * 512 + gcol;        \
        _Pragma("unroll")                                                        \
        for (int j_ = 0; j_ < 6; ++j_) {                                         \
            int g_ = wave + (j_ << 2);                                           \
            if (g_ < 21) gld16(gs_ + g_ * 8192, &stg[(BUF) * 10752 + g_ * 512]); \
        } }

#define G1STEP(S, CUR) {                                                         \
        float4 xna, xnb;                                                         \
        if ((S) < 15) {                                                          \
            xna = *(const float4*)(xrow + ((S) + 1) * 32);                       \
            xnb = *(const float4*)(xrow + ((S) + 1) * 32 + 4);                   \
            STAGE((CUR) ^ 1, (S) + 1)                                            \
        }                                                                        \
        bh8 af;                                                                  \
        af[0]=(short)f2b(xa.x); af[1]=(short)f2b(xa.y);                          \
        af[2]=(short)f2b(xa.z); af[3]=(short)f2b(xa.w);                          \
        af[4]=(short)f2b(xb.x); af[5]=(short)f2b(xb.y);                          \
        af[6]=(short)f2b(xb.z); af[7]=(short)f2b(xb.w);                          \
        const unsigned short* bp_ = &stg[(CUR) * 10752 + l16 * 32 + (quad << 3)];\
        _Pragma("unroll")                                                        \
        for (int t = 0; t < 21; ++t) {                                           \
            bh8 bf = *(const bh8*)&bp_[t * 512];                                 \
            acc[t] = MFMA16(af, bf, acc[t], 0, 0, 0);                            \
        }                                                                        \
        __syncthreads();                                                         \
        if ((S) < 15) { xa = xna; xb = xnb; }                                    \
    }

    STAGE(0, 0)
    float4 xa = *(const float4*)xrow;
    float4 xb = *(const float4*)(xrow + 4);
    __syncthreads();   // drains vmcnt -> stage 0 complete

#pragma unroll 1
    for (int sp = 0; sp < 8; ++sp) {
        G1STEP(2 * sp, 0)
        G1STEP(2 * sp + 1, 1)
    }
#undef G1STEP
#undef STAGE

    // ======== softmax(320) + hard_shrink + L1 norm (tiles 0..19), rows quad*4+r ========
    float mx[4], sm[4], s2[4];
#pragma unroll
    for (int r = 0; r < 4; ++r) mx[r] = acc[0][r];
#pragma unroll
    for (int t = 1; t < 20; ++t)
#pragma unroll
        for (int r = 0; r < 4; ++r) mx[r] = fmaxf(mx[r], acc[t][r]);
    for (int d = 1; d < 16; d <<= 1)
#pragma unroll
        for (int r = 0; r < 4; ++r) mx[r] = fmaxf(mx[r], __shfl_xor(mx[r], d));
#pragma unroll
    for (int r = 0; r < 4; ++r) sm[r] = 0.f;
#pragma unroll
    for (int t = 0; t < 20; ++t)
#pragma unroll
        for (int r = 0; r < 4; ++r) { float e = __expf(acc[t][r] - mx[r]); acc[t][r] = e; sm[r] += e; }
    for (int d = 1; d < 16; d <<= 1)
#pragma unroll
        for (int r = 0; r < 4; ++r) sm[r] += __shfl_xor(sm[r], d);
#pragma unroll
    for (int r = 0; r < 4; ++r) { s2[r] = 0.f; sm[r] = 1.f / sm[r]; }
#pragma unroll
    for (int t = 0; t < 20; ++t)
#pragma unroll
        for (int r = 0; r < 4; ++r) {
            float p  = acc[t][r] * sm[r];
            float hs = (p > SHRK) ? ((p - SHRK) * p / (p - SHRK + EPSV)) : 0.f;
            acc[t][r] = hs; s2[r] += hs;
        }
    for (int d = 1; d < 16; d <<= 1)
#pragma unroll
        for (int r = 0; r < 4; ++r) s2[r] += __shfl_xor(s2[r], d);
#pragma unroll
    for (int r = 0; r < 4; ++r) s2[r] = 1.f / fmaxf(s2[r], EPSV);
#pragma unroll
    for (int t = 0; t < 20; ++t)
#pragma unroll
        for (int r = 0; r < 4; ++r)
            attL[(m0 + quad * 4 + r) * 328 + t * 16 + l16] = f2b(acc[t][r] * s2[r]);

    // ======== level-3 class softmax from tile 20 (cols 0..9 live, 10..15 zero-padded) ========
#pragma unroll
    for (int r = 0; r < 4; ++r) {
        float v  = acc[20][r];
        float vm = (l16 < NCLS) ? v : -1e30f;
        for (int d = 1; d < 16; d <<= 1) vm = fmaxf(vm, __shfl_xor(vm, d));
        float e = (l16 < NCLS) ? __expf(v - vm) : 0.f;
        float ss = e;
        for (int d = 1; d < 16; d <<= 1) ss += __shfl_xor(ss, d);
        float p  = e / ss;
        float hs = (p > SHRK) ? ((p - SHRK) * p / (p - SHRK + EPSV)) : 0.f;
        float t2 = hs;
        for (int d = 1; d < 16; d <<= 1) t2 += __shfl_xor(t2, d);
        float a2 = hs / fmaxf(t2, EPSV);
        int row = m0 + quad * 4 + r;
        if (l16 < NCLS) out1[(rowbase + row) * 10 + l16] = a2;
        att2L[row * 40 + l16] = f2b(a2);       // classes 10..15 exactly 0
        att2L[row * 40 + 16 + l16] = 0;        // zero k = 16..31 (K pad to 32)
    }
    __syncthreads();   // att + att2 visible; stage area retired

    // ======== GEMM2: output_part = att @ W  (M=64,N=512,K=320) ========
    // waves split N (128 cols each, in 2 halves of 64); B read once, direct from L2, ping-pong prefetch
#pragma unroll 1
    for (int h2 = 0; h2 < 2; ++h2) {
        const unsigned short* wtb = Wt + ((long)((wave << 7) + (h2 << 6) + l16)) * MEM + (quad << 3);
        f4 c2[4][4];
#pragma unroll
        for (int m = 0; m < 4; ++m)
#pragma unroll
            for (int n = 0; n < 4; ++n) c2[m][n] = (f4){0.f, 0.f, 0.f, 0.f};
        bh8 bA[4], bB[4];
#pragma unroll
        for (int nt = 0; nt < 4; ++nt) bA[nt] = *(const bh8*)&wtb[nt * 5120];

#define G2STEP(S, BU, BN) {                                                           \
        bh8 a_[4];                                                                    \
        _Pragma("unroll")                                                             \
        for (int m = 0; m < 4; ++m)                                                   \
            a_[m] = *(const bh8*)&attL[((m << 4) + l16) * 328 + ((S) << 5) + (quad << 3)]; \
        if ((S) < 9) {                                                               \
            _Pragma("unroll")                                                         \
            for (int nt = 0; nt < 4; ++nt)                                            \
                BN[nt] = *(const bh8*)&wtb[nt * 5120 + (((S) + 1) << 5)];             \
        }                                                                             \
        _Pragma("unroll")                                                             \
        for (int nt = 0; nt < 4; ++nt) {                                              \
            _Pragma("unroll")                                                         \
            for (int m = 0; m < 4; ++m)                                               \
                c2[m][nt] = MFMA16(a_[m], BU[nt], c2[m][nt], 0, 0, 0);                \
        } }

        G2STEP(0, bA, bB) G2STEP(1, bB, bA) G2STEP(2, bA, bB) G2STEP(3, bB, bA)
        G2STEP(4, bA, bB) G2STEP(5, bB, bA) G2STEP(6, bA, bB) G2STEP(7, bB, bA)
        G2STEP(8, bA, bB) G2STEP(9, bB, bA)
#undef G2STEP

#pragma unroll
        for (int m = 0; m < 4; ++m)
#pragma unroll
            for (int nt = 0; nt < 4; ++nt)
#pragma unroll
                for (int r = 0; r < 4; ++r)
                    out3[(rowbase + (m << 4) + (quad << 2) + r) * FEA
                         + (wave << 7) + (h2 << 6) + (nt << 4) + l16] = c2[m][nt][r];
    }

    // ======== output_sem = att2 @ sem  (M=64,N=512,K=32 zero-padded) ========
    // same N-split; B direct from precomputed bf16 semTb [512][32]; single K-step
    bh8 sa[4];
#pragma unroll
    for (int m = 0; m < 4; ++m)
        sa[m] = *(const bh8*)&att2L[((m << 4) + l16) * 40 + (quad << 3)];
    const unsigned short* stb = semTb + ((wave << 7) + l16) * 32 + (quad << 3);
#pragma unroll
    for (int nt = 0; nt < 8; ++nt) {
        bh8 bf = *(const bh8*)&stb[nt << 9];   // 16 rows * 32 halfs
#pragma unroll
        for (int m = 0; m < 4; ++m) {
            f4 o = MFMA16(sa[m], bf, (f4){0.f, 0.f, 0.f, 0.f}, 0, 0, 0);
#pragma unroll
            for (int r = 0; r < 4; ++r)
                out0[(rowbase + (m << 4) + (quad << 2) + r) * FEA
                     + (wave << 7) + (nt << 4) + l16] = o[r];
        }
    }
}

extern "C" void kernel_launch(void* const* d_in, const int* in_sizes, int n_in,
                              void* d_out, int out_size, void* d_ws, size_t ws_size,
                              hipStream_t stream) {
    const float* x  = (const float*)d_in[0];
    const float* W  = (const float*)d_in[1];
    const float* wp = (const float*)d_in[2];
    const float* bp = (const float*)d_in[3];
    const float* wi = (const float*)d_in[4];
    const float* bi = (const float*)d_in[5];
    float* out = (float*)d_out;
    const long o1 = (long)NR * FEA;           // output_sem size
    const long o2 = o1 + (long)NR * NCLS;     // + att2
    const long o3 = o2 + (long)NCLS * FEA;    // + sem_att

    unsigned short* Wb2   = (unsigned short*)d_ws;      // [336][512] bf16
    unsigned short* Wt    = Wb2 + NW * FEA;             // [512][320] bf16
    unsigned short* semTb = Wt + FEA * MEM;             // [512][32]  bf16

    cast_w<<<672, 256, 0, stream>>>(W, Wb2, Wt);
    sem_kernel<<<8, 64, 0, stream>>>(W, wp, bp, wi, bi, Wb2, semTb, out + o2);
    fused_kernel<<<2048, 256, 0, stream>>>(x, Wb2, Wt, semTb, out, out + o1, out + o3);
}